// Round 3
// baseline (1261.232 us; speedup 1.0000x reference)
//
#include <hip/hip_runtime.h>

#define N_NODES 50000
#define N_EDGES 800000
#define BATCH   4
#define DIM     64
#define NEG_SLOPE 0.2f

// ---------------------------------------------------------------------------
// Index dtype detector (int64 vs int32): if int64 little-endian with values
// < 2^31, every odd 32-bit word is 0. Writes flag=1 for int64, 0 for int32.
// ---------------------------------------------------------------------------
__global__ void detect_idx_kernel(const unsigned* __restrict__ ei, int* flag) {
    __shared__ int any;
    if (threadIdx.x == 0) any = 0;
    __syncthreads();
    unsigned v = ei[threadIdx.x * 2 + 1];
    if (v != 0) atomicOr(&any, 1);
    __syncthreads();
    if (threadIdx.x == 0) *flag = (any ? 0 : 1);
}

__device__ __forceinline__ int load_idx(const void* p, long long i, int is64) {
    if (is64) return (int)(((const long long*)p)[i]);
    return ((const int*)p)[i];
}

// ---------------------------------------------------------------------------
// CSR build step 1: deg[row]++ over one graph's edges.
// ---------------------------------------------------------------------------
__global__ __launch_bounds__(256)
void histogram_kernel(const void* __restrict__ ei, const int* __restrict__ flag,
                      int b, int* __restrict__ deg) {
    const int is64 = *flag;
    const long long base = (long long)b * (2LL * N_EDGES);
    long long i = (long long)blockIdx.x * blockDim.x + threadIdx.x;
    long long stride = (long long)gridDim.x * blockDim.x;
    for (; i < N_EDGES; i += stride) {
        int row = load_idx(ei, base + i, is64);
        atomicAdd(&deg[row], 1);
    }
}

// ---------------------------------------------------------------------------
// CSR build step 2: exclusive scan of deg -> rowptr (N+1) and cursor copy.
// Single block, thread-coarsened: 1024 threads x 49 serial elements each,
// one 10-step block scan of partials. ~20 barriers total (was ~490).
// ---------------------------------------------------------------------------
__global__ __launch_bounds__(1024)
void scan_kernel(const int* __restrict__ deg, int* __restrict__ rowptr,
                 int* __restrict__ cursor) {
    __shared__ int sums[1024];
    const int C = 49;                       // ceil(50000/1024)
    int t = threadIdx.x;
    int start = t * C;
    int s = 0;
    for (int i = 0; i < C; ++i) {
        int idx = start + i;
        if (idx < N_NODES) s += deg[idx];
    }
    sums[t] = s;
    __syncthreads();
    for (int off = 1; off < 1024; off <<= 1) {
        int x = (t >= off) ? sums[t - off] : 0;
        __syncthreads();
        sums[t] += x;
        __syncthreads();
    }
    int run = sums[t] - s;                  // exclusive prefix for this chunk
    for (int i = 0; i < C; ++i) {
        int idx = start + i;
        if (idx < N_NODES) {
            rowptr[idx] = run;
            cursor[idx] = run;
            run += deg[idx];
        }
    }
    if (t == 1023) rowptr[N_NODES] = run;   // chunk start >= N, run == total
}

// ---------------------------------------------------------------------------
// CSR build step 3: place (col, weight) pairs sorted by row via cursor.
// ---------------------------------------------------------------------------
__global__ __launch_bounds__(256)
void placement_kernel(const void* __restrict__ ei, const float* __restrict__ ew,
                      const int* __restrict__ flag, int b,
                      int* __restrict__ cursor, int2* __restrict__ colw) {
    const int is64 = *flag;
    const long long base = (long long)b * (2LL * N_EDGES);
    const float* ewb = ew + (long long)b * N_EDGES;
    long long i = (long long)blockIdx.x * blockDim.x + threadIdx.x;
    long long stride = (long long)gridDim.x * blockDim.x;
    for (; i < N_EDGES; i += stride) {
        int row = load_idx(ei, base + i, is64);
        int col = load_idx(ei, base + N_EDGES + i, is64);
        int pos = atomicAdd(&cursor[row], 1);
        colw[pos] = make_int2(col, __float_as_int(ewb[i]));
    }
}

// ---------------------------------------------------------------------------
// S = act(X) @ W. W staged in LDS; each thread computes 4 consecutive output
// cols for a row (ds_read_b128 for W, float4 store). Block = 256 thr, 64 rows.
// ---------------------------------------------------------------------------
template <bool LEAKY>
__global__ __launch_bounds__(256)
void gemm_kernel(const float* __restrict__ X, const float* __restrict__ W,
                 float* __restrict__ S) {
    __shared__ float Wl[64 * 64];
    int t = threadIdx.x;
    for (int i = t; i < 64 * 64; i += 256) Wl[i] = W[i];
    __syncthreads();

    int dq = t & 15;       // output col quad: cols 4*dq .. 4*dq+3
    int rl = t >> 4;       // local row 0..15
    int rowBase = blockIdx.x * 64;
    for (int r = rl; r < 64; r += 16) {
        int row = rowBase + r;
        if (row >= N_NODES) break;
        const float* xr = X + (long long)row * DIM;
        float4 acc = {0.f, 0.f, 0.f, 0.f};
#pragma unroll
        for (int k = 0; k < 64; k += 4) {
            float4 xv = *(const float4*)(xr + k);
            if (LEAKY) {
                xv.x = xv.x > 0.f ? xv.x : NEG_SLOPE * xv.x;
                xv.y = xv.y > 0.f ? xv.y : NEG_SLOPE * xv.y;
                xv.z = xv.z > 0.f ? xv.z : NEG_SLOPE * xv.z;
                xv.w = xv.w > 0.f ? xv.w : NEG_SLOPE * xv.w;
            }
#pragma unroll
            for (int kk = 0; kk < 4; ++kk) {
                float xs = kk == 0 ? xv.x : kk == 1 ? xv.y : kk == 2 ? xv.z : xv.w;
                float4 wv = *(const float4*)(&Wl[(k + kk) * 64 + dq * 4]);
                acc.x += xs * wv.x;
                acc.y += xs * wv.y;
                acc.z += xs * wv.z;
                acc.w += xs * wv.w;
            }
        }
        *(float4*)(S + (long long)row * DIM + dq * 4) = acc;
    }
}

// ---------------------------------------------------------------------------
// Pull aggregation: one wave per node, lane = feature. Unroll 8 for MLP.
// dst[node][lane] = bias[lane] + sum_e w_e * src[col_e][lane]
// ---------------------------------------------------------------------------
__global__ __launch_bounds__(256)
void aggregate_kernel(const int* __restrict__ rowptr, const int2* __restrict__ colw,
                      const float* __restrict__ src, const float* __restrict__ bias,
                      float* __restrict__ dst) {
    int lane = threadIdx.x & 63;
    int node = blockIdx.x * 4 + (threadIdx.x >> 6);
    if (node >= N_NODES) return;
    int s = rowptr[node];
    int e = rowptr[node + 1];
    float acc = bias[lane];
    int k = s;
    for (; k + 8 <= e; k += 8) {
        int2 c[8];
        float v[8];
#pragma unroll
        for (int j = 0; j < 8; ++j) c[j] = colw[k + j];
#pragma unroll
        for (int j = 0; j < 8; ++j) v[j] = src[(long long)c[j].x * DIM + lane];
#pragma unroll
        for (int j = 0; j < 8; ++j) acc += __int_as_float(c[j].y) * v[j];
    }
    for (; k < e; ++k) {
        int2 c = colw[k];
        acc += __int_as_float(c.y) * src[(long long)c.x * DIM + lane];
    }
    dst[(long long)node * DIM + lane] = acc;
}

extern "C" void kernel_launch(void* const* d_in, const int* in_sizes, int n_in,
                              void* d_out, int out_size, void* d_ws, size_t ws_size,
                              hipStream_t stream) {
    const float* bx = (const float*)d_in[0];
    const void*  ei = d_in[1];
    const float* ew = (const float*)d_in[2];
    const float* W0 = (const float*)d_in[3];
    const float* b0 = (const float*)d_in[4];
    const float* W1 = (const float*)d_in[5];
    const float* b1 = (const float*)d_in[6];
    float* out = (float*)d_out;

    // workspace layout
    char* ws = (char*)d_ws;
    int*   flag    = (int*)ws;                           // [0, 256)
    int*   deg     = (int*)(ws + 256);                   // 50048 ints
    int*   cursor  = deg + 50048;
    int*   rowptr  = cursor + 50048;                     // 50001 ints (padded)
    int2*  colw    = (int2*)(ws + 600832);               // 800000 int2 = 6.4 MB
    float* support0 = (float*)(ws + 7000832);            // 12.8 MB
    const size_t NEED_FULL = 32600832;                   // + separate support1
    const bool bigWS = (ws_size >= NEED_FULL);
    float* support1 = bigWS ? (float*)(ws + 19800832) : support0;
    const long long ND = (long long)N_NODES * DIM;

    detect_idx_kernel<<<1, 64, 0, stream>>>((const unsigned*)ei, flag);

    // layer-1 support is graph-independent: compute once if ws allows
    if (bigWS)
        gemm_kernel<false><<<(N_NODES + 63) / 64, 256, 0, stream>>>(bx, W0, support0);

    for (int b = 0; b < BATCH; ++b) {
        float* outb = out + (long long)b * ND;

        // --- build CSR for graph b (shared by both layers) ---
        hipMemsetAsync(deg, 0, N_NODES * sizeof(int), stream);
        histogram_kernel<<<1024, 256, 0, stream>>>(ei, flag, b, deg);
        scan_kernel<<<1, 1024, 0, stream>>>(deg, rowptr, cursor);
        placement_kernel<<<1024, 256, 0, stream>>>(ei, ew, flag, b, cursor, colw);

        // --- layer 1: h1 = A_b @ support0 + b0 (pre-activation) ---
        if (!bigWS)
            gemm_kernel<false><<<(N_NODES + 63) / 64, 256, 0, stream>>>(bx, W0, support0);
        aggregate_kernel<<<(N_NODES + 3) / 4, 256, 0, stream>>>(rowptr, colw, support0,
                                                                b0, outb);

        // --- layer 2: support1 = leaky(h1) @ W1 ; out = A_b @ support1 + b1 ---
        gemm_kernel<true><<<(N_NODES + 63) / 64, 256, 0, stream>>>(outb, W1, support1);
        aggregate_kernel<<<(N_NODES + 3) / 4, 256, 0, stream>>>(rowptr, colw, support1,
                                                                b1, outb);
    }
}

// Round 4
// 745.994 us; speedup vs baseline: 1.6907x; 1.6907x over previous
//
#include <hip/hip_runtime.h>

#define N_NODES 50000
#define N_EDGES 800000
#define BATCH   4
#define DIM     64
#define NEG_SLOPE 0.2f
#define NTOT    (BATCH * N_NODES)          // 200000 concatenated degree entries
#define SCAN_BLOCKS 196                    // ceil(200000 / 1024)

// ---------------------------------------------------------------------------
// Index dtype detector (int64 vs int32): if int64 little-endian with values
// < 2^31, every odd 32-bit word is 0. Writes flag=1 for int64, 0 for int32.
// ---------------------------------------------------------------------------
__global__ void detect_idx_kernel(const unsigned* __restrict__ ei, int* flag) {
    __shared__ int any;
    if (threadIdx.x == 0) any = 0;
    __syncthreads();
    unsigned v = ei[threadIdx.x * 2 + 1];
    if (v != 0) atomicOr(&any, 1);
    __syncthreads();
    if (threadIdx.x == 0) *flag = (any ? 0 : 1);
}

__device__ __forceinline__ int load_idx(const void* p, long long i, int is64) {
    if (is64) return (int)(((const long long*)p)[i]);
    return ((const int*)p)[i];
}

// ---------------------------------------------------------------------------
// Batched histogram: deg4[b][row]++ over all 4 graphs' edges in one pass.
// ---------------------------------------------------------------------------
__global__ __launch_bounds__(256)
void histogram_all_kernel(const void* __restrict__ ei, const int* __restrict__ flag,
                          int* __restrict__ deg4) {
    const int is64 = *flag;
    long long i = (long long)blockIdx.x * blockDim.x + threadIdx.x;
    long long stride = (long long)gridDim.x * blockDim.x;
    const long long total = (long long)BATCH * N_EDGES;
    for (; i < total; i += stride) {
        int b = (int)(i / N_EDGES);
        long long e = i - (long long)b * N_EDGES;
        int row = load_idx(ei, (long long)b * (2LL * N_EDGES) + e, is64);
        atomicAdd(&deg4[b * N_NODES + row], 1);
    }
}

// ---------------------------------------------------------------------------
// Hierarchical scan over deg4[200000] -> rowptr4 (exclusive) + cursor copy.
// Stage 1: per-block (1024 elems) reduce -> bsum[196]
// ---------------------------------------------------------------------------
__global__ __launch_bounds__(256)
void scan_partial_kernel(const int* __restrict__ deg, int* __restrict__ bsum) {
    __shared__ int sdata[256];
    int t = threadIdx.x;
    int base = blockIdx.x * 1024;
    int s = 0;
#pragma unroll
    for (int i = 0; i < 4; ++i) {
        int idx = base + i * 256 + t;           // coalesced
        if (idx < NTOT) s += deg[idx];
    }
    sdata[t] = s;
    __syncthreads();
    for (int off = 128; off > 0; off >>= 1) {
        if (t < off) sdata[t] += sdata[t + off];
        __syncthreads();
    }
    if (t == 0) bsum[blockIdx.x] = sdata[0];
}

// Stage 2: exclusive scan of bsum[196] in one small block; also rowptr[NTOT].
__global__ __launch_bounds__(256)
void scan_bsum_kernel(int* __restrict__ bsum, int* __restrict__ rowptr) {
    __shared__ int sdata[256];
    int t = threadIdx.x;
    int v = (t < SCAN_BLOCKS) ? bsum[t] : 0;
    sdata[t] = v;
    __syncthreads();
    for (int off = 1; off < 256; off <<= 1) {
        int x = (t >= off) ? sdata[t - off] : 0;
        __syncthreads();
        sdata[t] += x;
        __syncthreads();
    }
    if (t < SCAN_BLOCKS) bsum[t] = sdata[t] - v;     // exclusive block offset
    if (t == 255) rowptr[NTOT] = sdata[255];         // grand total
}

// Stage 3: apply — local exclusive scan per block + block offset.
__global__ __launch_bounds__(256)
void scan_apply_kernel(const int* __restrict__ deg, const int* __restrict__ bsum,
                       int* __restrict__ rowptr, int* __restrict__ cursor) {
    __shared__ int sdata[256];
    int t = threadIdx.x;
    int base = blockIdx.x * 1024 + t * 4;
    int v0 = 0, v1 = 0, v2 = 0, v3 = 0;
    if (base + 3 < NTOT) {
        int4 q = *(const int4*)(deg + base);
        v0 = q.x; v1 = q.y; v2 = q.z; v3 = q.w;
    } else {
        if (base + 0 < NTOT) v0 = deg[base + 0];
        if (base + 1 < NTOT) v1 = deg[base + 1];
        if (base + 2 < NTOT) v2 = deg[base + 2];
        if (base + 3 < NTOT) v3 = deg[base + 3];
    }
    int s = v0 + v1 + v2 + v3;
    sdata[t] = s;
    __syncthreads();
    for (int off = 1; off < 256; off <<= 1) {
        int x = (t >= off) ? sdata[t - off] : 0;
        __syncthreads();
        sdata[t] += x;
        __syncthreads();
    }
    int run = bsum[blockIdx.x] + sdata[t] - s;
    if (base + 0 < NTOT) { rowptr[base + 0] = run; cursor[base + 0] = run; run += v0; }
    if (base + 1 < NTOT) { rowptr[base + 1] = run; cursor[base + 1] = run; run += v1; }
    if (base + 2 < NTOT) { rowptr[base + 2] = run; cursor[base + 2] = run; run += v2; }
    if (base + 3 < NTOT) { rowptr[base + 3] = run; cursor[base + 3] = run; run += v3; }
}

// ---------------------------------------------------------------------------
// Placement for graph b: (col, weight) into per-graph colw via global cursor.
// Global CSR base of graph b is exactly b*N_EDGES (each graph has E edges).
// ---------------------------------------------------------------------------
__global__ __launch_bounds__(256)
void placement_kernel(const void* __restrict__ ei, const float* __restrict__ ew,
                      const int* __restrict__ flag, int b,
                      int* __restrict__ cursor4, int2* __restrict__ colw) {
    const int is64 = *flag;
    const long long base = (long long)b * (2LL * N_EDGES);
    const float* ewb = ew + (long long)b * N_EDGES;
    int* cur = cursor4 + b * N_NODES;
    const int gbase = b * N_EDGES;
    long long i = (long long)blockIdx.x * blockDim.x + threadIdx.x;
    long long stride = (long long)gridDim.x * blockDim.x;
    for (; i < N_EDGES; i += stride) {
        int row = load_idx(ei, base + i, is64);
        int col = load_idx(ei, base + N_EDGES + i, is64);
        int pos = atomicAdd(&cur[row], 1) - gbase;
        colw[pos] = make_int2(col, __float_as_int(ewb[i]));
    }
}

// ---------------------------------------------------------------------------
// S = act(X) @ W. W staged in LDS; each thread computes 4 consecutive output
// cols for a row (ds_read_b128 for W, float4 store). Block = 256 thr, 64 rows.
// ---------------------------------------------------------------------------
template <bool LEAKY>
__global__ __launch_bounds__(256)
void gemm_kernel(const float* __restrict__ X, const float* __restrict__ W,
                 float* __restrict__ S) {
    __shared__ float Wl[64 * 64];
    int t = threadIdx.x;
    for (int i = t; i < 64 * 64; i += 256) Wl[i] = W[i];
    __syncthreads();

    int dq = t & 15;
    int rl = t >> 4;
    int rowBase = blockIdx.x * 64;
    for (int r = rl; r < 64; r += 16) {
        int row = rowBase + r;
        if (row >= N_NODES) break;
        const float* xr = X + (long long)row * DIM;
        float4 acc = {0.f, 0.f, 0.f, 0.f};
#pragma unroll
        for (int k = 0; k < 64; k += 4) {
            float4 xv = *(const float4*)(xr + k);
            if (LEAKY) {
                xv.x = xv.x > 0.f ? xv.x : NEG_SLOPE * xv.x;
                xv.y = xv.y > 0.f ? xv.y : NEG_SLOPE * xv.y;
                xv.z = xv.z > 0.f ? xv.z : NEG_SLOPE * xv.z;
                xv.w = xv.w > 0.f ? xv.w : NEG_SLOPE * xv.w;
            }
#pragma unroll
            for (int kk = 0; kk < 4; ++kk) {
                float xs = kk == 0 ? xv.x : kk == 1 ? xv.y : kk == 2 ? xv.z : xv.w;
                float4 wv = *(const float4*)(&Wl[(k + kk) * 64 + dq * 4]);
                acc.x += xs * wv.x;
                acc.y += xs * wv.y;
                acc.z += xs * wv.z;
                acc.w += xs * wv.w;
            }
        }
        *(float4*)(S + (long long)row * DIM + dq * 4) = acc;
    }
}

// ---------------------------------------------------------------------------
// Pull aggregation: one wave per node, lane = feature.
// dst[node][lane] = bias[lane] + sum_e w_e * src[col_e][lane]
// rowptr is graph-local view (rowptr4 + b*N_NODES), gbase = b*N_EDGES.
// ---------------------------------------------------------------------------
__global__ __launch_bounds__(256)
void aggregate_kernel(const int* __restrict__ rowptr, int gbase,
                      const int2* __restrict__ colw,
                      const float* __restrict__ src, const float* __restrict__ bias,
                      float* __restrict__ dst) {
    int lane = threadIdx.x & 63;
    int node = blockIdx.x * 4 + (threadIdx.x >> 6);
    if (node >= N_NODES) return;
    int s = rowptr[node] - gbase;
    int e = rowptr[node + 1] - gbase;
    float acc = bias[lane];
    int k = s;
    for (; k + 8 <= e; k += 8) {
        int2 c[8];
        float v[8];
#pragma unroll
        for (int j = 0; j < 8; ++j) c[j] = colw[k + j];
#pragma unroll
        for (int j = 0; j < 8; ++j) v[j] = src[(long long)c[j].x * DIM + lane];
#pragma unroll
        for (int j = 0; j < 8; ++j) acc += __int_as_float(c[j].y) * v[j];
    }
    for (; k < e; ++k) {
        int2 c = colw[k];
        acc += __int_as_float(c.y) * src[(long long)c.x * DIM + lane];
    }
    dst[(long long)node * DIM + lane] = acc;
}

extern "C" void kernel_launch(void* const* d_in, const int* in_sizes, int n_in,
                              void* d_out, int out_size, void* d_ws, size_t ws_size,
                              hipStream_t stream) {
    const float* bx = (const float*)d_in[0];
    const void*  ei = d_in[1];
    const float* ew = (const float*)d_in[2];
    const float* W0 = (const float*)d_in[3];
    const float* b0 = (const float*)d_in[4];
    const float* W1 = (const float*)d_in[5];
    const float* b1 = (const float*)d_in[6];
    float* out = (float*)d_out;

    // workspace layout (~20.6 MB total; R0 proved >=25.7 MB available)
    char* ws = (char*)d_ws;
    int*   flag    = (int*)ws;                 // [0,4)
    int*   bsum    = (int*)(ws + 64);          // 196 ints
    int*   deg4    = (int*)(ws + 1024);        // 200704 ints (padded)
    int*   cursor4 = deg4 + 200704;            // 200704 ints
    int*   rowptr4 = cursor4 + 200704;         // 200001 ints (padded 200704)
    int2*  colw    = (int2*)(rowptr4 + 200704);          // 800000 int2 = 6.4 MB
    float* support0 = (float*)((char*)colw + (long long)N_EDGES * 8);  // 12.8 MB
    const long long ND = (long long)N_NODES * DIM;

    detect_idx_kernel<<<1, 64, 0, stream>>>((const unsigned*)ei, flag);

    // --- batched CSR skeleton for all 4 graphs ---
    hipMemsetAsync(deg4, 0, NTOT * sizeof(int), stream);
    histogram_all_kernel<<<2048, 256, 0, stream>>>(ei, flag, deg4);
    scan_partial_kernel<<<SCAN_BLOCKS, 256, 0, stream>>>(deg4, bsum);
    scan_bsum_kernel<<<1, 256, 0, stream>>>(bsum, rowptr4);
    scan_apply_kernel<<<SCAN_BLOCKS, 256, 0, stream>>>(deg4, bsum, rowptr4, cursor4);

    // --- layer-1 support: graph-independent, once ---
    gemm_kernel<false><<<(N_NODES + 63) / 64, 256, 0, stream>>>(bx, W0, support0);

    for (int b = 0; b < BATCH; ++b) {
        float* outb = out + (long long)b * ND;
        // support1 scratch: next graph's (not yet finalized) out slice, or
        // support0 for the last graph (no longer needed afterwards).
        float* support1 = (b < BATCH - 1) ? out + (long long)(b + 1) * ND : support0;

        placement_kernel<<<1024, 256, 0, stream>>>(ei, ew, flag, b, cursor4, colw);

        // layer 1: h1 = A_b @ support0 + b0 (pre-activation)
        aggregate_kernel<<<(N_NODES + 3) / 4, 256, 0, stream>>>(
            rowptr4 + b * N_NODES, b * N_EDGES, colw, support0, b0, outb);

        // layer 2: support1 = leaky(h1) @ W1 ; out = A_b @ support1 + b1
        gemm_kernel<true><<<(N_NODES + 63) / 64, 256, 0, stream>>>(outb, W1, support1);
        aggregate_kernel<<<(N_NODES + 3) / 4, 256, 0, stream>>>(
            rowptr4 + b * N_NODES, b * N_EDGES, colw, support1, b1, outb);
    }
}

// Round 5
// 693.964 us; speedup vs baseline: 1.8174x; 1.0750x over previous
//
#include <hip/hip_runtime.h>
#include <hip/hip_fp16.h>

#define N_NODES 50000
#define NROW    50176                    // padded rows per graph (multiple of 1024)
#define N_EDGES 800000
#define BATCH   4
#define DIM     64
#define NEG_SLOPE 0.2f
#define K_CHUNK 16
#define CHUNK_E (N_EDGES / K_CHUNK)      // 50000 exactly
#define NTOT2   (BATCH * NROW)           // 200704 = 196*1024 exactly
#define SCAN_BLOCKS (NTOT2 / 1024)       // 196
#define HALF_ROWS 25088                  // NROW/2
#define HALF_WORDS 12544                 // HALF_ROWS/2 packed u16 words

// ---------------------------------------------------------------------------
// Index dtype detector (int64 vs int32): if int64 little-endian with values
// < 2^31, every odd 32-bit word is 0. flag=1 for int64, 0 for int32.
// ---------------------------------------------------------------------------
__global__ void detect_idx_kernel(const unsigned* __restrict__ ei, int* flag) {
    __shared__ int any;
    if (threadIdx.x == 0) any = 0;
    __syncthreads();
    unsigned v = ei[threadIdx.x * 2 + 1];
    if (v != 0) atomicOr(&any, 1);
    __syncthreads();
    if (threadIdx.x == 0) *flag = (any ? 0 : 1);
}

__device__ __forceinline__ int load_idx(const void* p, long long i, int is64) {
    if (is64) return (int)(((const long long*)p)[i]);
    return ((const int*)p)[i];
}

// ---------------------------------------------------------------------------
// Atomic-free histogram stage 1: private LDS histogram per (graph, chunk, half).
// u16 counters packed in u32 (chunk has 50000 edges -> max count < 65536).
// Dump coalesced partials to P32[(b*16+k)][half]. No global atomics.
// ---------------------------------------------------------------------------
__global__ __launch_bounds__(256)
void hist_partial_kernel(const void* __restrict__ ei, const int* __restrict__ flag,
                         unsigned* __restrict__ P32) {
    __shared__ unsigned lds[HALF_WORDS];          // 50 KB
    int t = threadIdx.x;
    int b = blockIdx.x >> 5;
    int k = (blockIdx.x >> 1) & (K_CHUNK - 1);
    int h = blockIdx.x & 1;
    for (int i = t; i < HALF_WORDS; i += 256) lds[i] = 0;
    __syncthreads();
    const int is64 = *flag;
    const int rowLo = h * HALF_ROWS;
    const long long base = (long long)b * 2LL * N_EDGES + (long long)k * CHUNK_E;
    for (int i = t; i < CHUNK_E; i += 256) {
        int row = load_idx(ei, base + i, is64);
        unsigned r = (unsigned)(row - rowLo);
        if (r < HALF_ROWS)
            atomicAdd(&lds[r >> 1], 1u << ((r & 1) * 16));
    }
    __syncthreads();
    unsigned* dst = P32 + (long long)(b * K_CHUNK + k) * (NROW / 2) + h * HALF_WORDS;
    for (int i = t; i < HALF_WORDS; i += 256) dst[i] = lds[i];
}

// Stage 2: deg4[b][row] = sum_k P16[b][k][row]  (coalesced u16 reads)
__global__ __launch_bounds__(256)
void merge_deg_kernel(const unsigned short* __restrict__ P16, int* __restrict__ deg4) {
    int gid = blockIdx.x * 256 + threadIdx.x;
    if (gid >= NTOT2) return;
    int b = gid / NROW;
    int row = gid - b * NROW;
    const unsigned short* p = P16 + (long long)(b * K_CHUNK) * NROW + row;
    int s = 0;
#pragma unroll
    for (int k = 0; k < K_CHUNK; ++k) s += p[(long long)k * NROW];
    deg4[gid] = s;
}

// ---------------------------------------------------------------------------
// Hierarchical exclusive scan over deg4[NTOT2] -> rowptr4 + cursor4.
// ---------------------------------------------------------------------------
__global__ __launch_bounds__(256)
void scan_partial_kernel(const int* __restrict__ deg, int* __restrict__ bsum) {
    __shared__ int sdata[256];
    int t = threadIdx.x;
    int base = blockIdx.x * 1024;
    int s = 0;
#pragma unroll
    for (int i = 0; i < 4; ++i) {
        int idx = base + i * 256 + t;
        if (idx < NTOT2) s += deg[idx];
    }
    sdata[t] = s;
    __syncthreads();
    for (int off = 128; off > 0; off >>= 1) {
        if (t < off) sdata[t] += sdata[t + off];
        __syncthreads();
    }
    if (t == 0) bsum[blockIdx.x] = sdata[0];
}

__global__ __launch_bounds__(256)
void scan_bsum_kernel(int* __restrict__ bsum, int* __restrict__ rowptr) {
    __shared__ int sdata[256];
    int t = threadIdx.x;
    int v = (t < SCAN_BLOCKS) ? bsum[t] : 0;
    sdata[t] = v;
    __syncthreads();
    for (int off = 1; off < 256; off <<= 1) {
        int x = (t >= off) ? sdata[t - off] : 0;
        __syncthreads();
        sdata[t] += x;
        __syncthreads();
    }
    if (t < SCAN_BLOCKS) bsum[t] = sdata[t] - v;
    if (t == 255) rowptr[NTOT2] = sdata[255];
}

__global__ __launch_bounds__(256)
void scan_apply_kernel(const int* __restrict__ deg, const int* __restrict__ bsum,
                       int* __restrict__ rowptr, int* __restrict__ cursor) {
    __shared__ int sdata[256];
    int t = threadIdx.x;
    int base = blockIdx.x * 1024 + t * 4;
    int4 q = *(const int4*)(deg + base);          // NTOT2 is an exact multiple
    int s = q.x + q.y + q.z + q.w;
    sdata[t] = s;
    __syncthreads();
    for (int off = 1; off < 256; off <<= 1) {
        int x = (t >= off) ? sdata[t - off] : 0;
        __syncthreads();
        sdata[t] += x;
        __syncthreads();
    }
    int run = bsum[blockIdx.x] + sdata[t] - s;
    rowptr[base + 0] = run; cursor[base + 0] = run; run += q.x;
    rowptr[base + 1] = run; cursor[base + 1] = run; run += q.y;
    rowptr[base + 2] = run; cursor[base + 2] = run; run += q.z;
    rowptr[base + 3] = run; cursor[base + 3] = run; run += q.w;
}

// ---------------------------------------------------------------------------
// Placement: (col, weight) pairs via global cursor atomics.
// big path: nGraphs=4, sub=0 (global positions). small: nGraphs=1, sub=b*E.
// ---------------------------------------------------------------------------
__global__ __launch_bounds__(256)
void placement_kernel(const void* __restrict__ ei, const float* __restrict__ ew,
                      const int* __restrict__ flag, int nGraphs, int bStart,
                      int* __restrict__ cursor4, int2* __restrict__ colw, int sub) {
    const int is64 = *flag;
    long long i = (long long)blockIdx.x * blockDim.x + threadIdx.x;
    long long stride = (long long)gridDim.x * blockDim.x;
    const long long total = (long long)nGraphs * N_EDGES;
    for (; i < total; i += stride) {
        int g = (int)(i / N_EDGES);
        long long e = i - (long long)g * N_EDGES;
        int b = bStart + g;
        long long base = (long long)b * 2LL * N_EDGES;
        int row = load_idx(ei, base + e, is64);
        int col = load_idx(ei, base + N_EDGES + e, is64);
        float w = ew[(long long)b * N_EDGES + e];
        int pos = atomicAdd(&cursor4[b * NROW + row], 1) - sub;
        colw[pos] = make_int2(col, __float_as_int(w));
    }
}

// ---------------------------------------------------------------------------
// S = act(X) @ W  -> fp16 output. W in LDS; thread = (row, col-quad).
// ---------------------------------------------------------------------------
template <bool LEAKY>
__global__ __launch_bounds__(256)
void gemm_kernel(const float* __restrict__ X, const float* __restrict__ W,
                 __half* __restrict__ S) {
    __shared__ float Wl[64 * 64];
    int t = threadIdx.x;
    for (int i = t; i < 64 * 64; i += 256) Wl[i] = W[i];
    __syncthreads();

    int dq = t & 15;
    int rl = t >> 4;
    int rowBase = blockIdx.x * 64;
    for (int r = rl; r < 64; r += 16) {
        int row = rowBase + r;
        if (row >= N_NODES) break;
        const float* xr = X + (long long)row * DIM;
        float4 acc = {0.f, 0.f, 0.f, 0.f};
#pragma unroll
        for (int k = 0; k < 64; k += 4) {
            float4 xv = *(const float4*)(xr + k);
            if (LEAKY) {
                xv.x = xv.x > 0.f ? xv.x : NEG_SLOPE * xv.x;
                xv.y = xv.y > 0.f ? xv.y : NEG_SLOPE * xv.y;
                xv.z = xv.z > 0.f ? xv.z : NEG_SLOPE * xv.z;
                xv.w = xv.w > 0.f ? xv.w : NEG_SLOPE * xv.w;
            }
#pragma unroll
            for (int kk = 0; kk < 4; ++kk) {
                float xs = kk == 0 ? xv.x : kk == 1 ? xv.y : kk == 2 ? xv.z : xv.w;
                float4 wv = *(const float4*)(&Wl[(k + kk) * 64 + dq * 4]);
                acc.x += xs * wv.x;
                acc.y += xs * wv.y;
                acc.z += xs * wv.z;
                acc.w += xs * wv.w;
            }
        }
        __half2* o = (__half2*)(S + (long long)row * DIM + dq * 4);
        o[0] = __floats2half2_rn(acc.x, acc.y);
        o[1] = __floats2half2_rn(acc.z, acc.w);
    }
}

// ---------------------------------------------------------------------------
// Pull aggregation (fp16 src, f32 accum): wave per node, lane = feature.
// colwLocal: colw positions are graph-local (subtract b*E from rowptr).
// Grid = nGraphs * (NROW/4) blocks.
// ---------------------------------------------------------------------------
__global__ __launch_bounds__(256)
void aggregate_kernel(const int* __restrict__ rowptr4, const int2* __restrict__ colw,
                      const __half* __restrict__ src, const float* __restrict__ bias,
                      float* __restrict__ dstBase, int bStart, int colwLocal) {
    const int BLKS = NROW / 4;                     // 12544
    int bi = blockIdx.x / BLKS;
    int node = (blockIdx.x % BLKS) * 4 + (threadIdx.x >> 6);
    int lane = threadIdx.x & 63;
    int b = bStart + bi;
    if (node >= N_NODES) return;
    const int* rp = rowptr4 + b * NROW;
    int sub = colwLocal ? b * N_EDGES : 0;
    int s = rp[node] - sub;
    int e = rp[node + 1] - sub;
    float acc = bias[lane];
    int k = s;
    for (; k + 8 <= e; k += 8) {
        int2 c[8];
        float v[8];
#pragma unroll
        for (int j = 0; j < 8; ++j) c[j] = colw[k + j];
#pragma unroll
        for (int j = 0; j < 8; ++j) v[j] = __half2float(src[(long long)c[j].x * DIM + lane]);
#pragma unroll
        for (int j = 0; j < 8; ++j) acc += __int_as_float(c[j].y) * v[j];
    }
    for (; k < e; ++k) {
        int2 c = colw[k];
        acc += __int_as_float(c.y) * __half2float(src[(long long)c.x * DIM + lane]);
    }
    dstBase[(long long)b * N_NODES * DIM + (long long)node * DIM + lane] = acc;
}

extern "C" void kernel_launch(void* const* d_in, const int* in_sizes, int n_in,
                              void* d_out, int out_size, void* d_ws, size_t ws_size,
                              hipStream_t stream) {
    const float* bx = (const float*)d_in[0];
    const void*  ei = d_in[1];
    const float* ew = (const float*)d_in[2];
    const float* W0 = (const float*)d_in[3];
    const float* b0 = (const float*)d_in[4];
    const float* W1 = (const float*)d_in[5];
    const float* b1 = (const float*)d_in[6];
    float* out = (float*)d_out;

    // ---- workspace layout ----
    // [0,256)        flag
    // [256,1280)     bsum (196 ints)
    // [1280,804096)  deg4   (200704 ints)
    // [804096,1606912)   cursor4
    // [1606912,2409984)  rowptr4 (200705 ints, padded)
    // [2409984,8832512)  P16 partial hists (6.42 MB)  -> reused as fp16 support1
    // [8832512,15232512) support0 fp16 (6.4 MB)
    // [15232512,...)     colw: 25.6 MB (big, all graphs) or 6.4 MB (small)
    char* ws = (char*)d_ws;
    int*      flag     = (int*)ws;
    int*      bsum     = (int*)(ws + 256);
    int*      deg4     = (int*)(ws + 1280);
    int*      cursor4  = (int*)(ws + 804096);
    int*      rowptr4  = (int*)(ws + 1606912);
    unsigned* P32      = (unsigned*)(ws + 2409984);
    __half*   support1 = (__half*)(ws + 2409984);      // alias: P16 dead after merge
    __half*   support0 = (__half*)(ws + 8832512);
    int2*     colw     = (int2*)(ws + 15232512);
    const size_t NEED_BIG = 15232512ull + (size_t)BATCH * N_EDGES * 8ull; // 40.8 MB
    const bool big = ws_size >= NEED_BIG;
    const long long ND = (long long)N_NODES * DIM;

    detect_idx_kernel<<<1, 64, 0, stream>>>((const unsigned*)ei, flag);

    // ---- batched atomic-free CSR skeleton ----
    hist_partial_kernel<<<BATCH * K_CHUNK * 2, 256, 0, stream>>>(ei, flag, P32);
    merge_deg_kernel<<<(NTOT2 + 255) / 256, 256, 0, stream>>>(
        (const unsigned short*)P32, deg4);
    scan_partial_kernel<<<SCAN_BLOCKS, 256, 0, stream>>>(deg4, bsum);
    scan_bsum_kernel<<<1, 256, 0, stream>>>(bsum, rowptr4);
    scan_apply_kernel<<<SCAN_BLOCKS, 256, 0, stream>>>(deg4, bsum, rowptr4, cursor4);

    // ---- layer-1 support (graph-independent, fp16) ----
    gemm_kernel<false><<<(N_NODES + 63) / 64, 256, 0, stream>>>(bx, W0, support0);

    const int AGG_BLKS = NROW / 4;                 // 12544 per graph

    if (big) {
        // one placement + one layer-1 aggregate for all graphs
        placement_kernel<<<2048, 256, 0, stream>>>(ei, ew, flag, BATCH, 0,
                                                   cursor4, colw, 0);
        aggregate_kernel<<<BATCH * AGG_BLKS, 256, 0, stream>>>(
            rowptr4, colw, support0, b0, out, 0, 0);
        for (int b = 0; b < BATCH; ++b) {
            gemm_kernel<true><<<(N_NODES + 63) / 64, 256, 0, stream>>>(
                out + (long long)b * ND, W1, support1);
            aggregate_kernel<<<AGG_BLKS, 256, 0, stream>>>(
                rowptr4, colw, support1, b1, out, b, 0);
        }
    } else {
        for (int b = 0; b < BATCH; ++b) {
            placement_kernel<<<1024, 256, 0, stream>>>(ei, ew, flag, 1, b,
                                                       cursor4, colw, b * N_EDGES);
            aggregate_kernel<<<AGG_BLKS, 256, 0, stream>>>(
                rowptr4, colw, support0, b0, out, b, 1);
            gemm_kernel<true><<<(N_NODES + 63) / 64, 256, 0, stream>>>(
                out + (long long)b * ND, W1, support1);
            aggregate_kernel<<<AGG_BLKS, 256, 0, stream>>>(
                rowptr4, colw, support1, b1, out, b, 1);
        }
    }
}

// Round 6
// 531.419 us; speedup vs baseline: 2.3733x; 1.3059x over previous
//
#include <hip/hip_runtime.h>
#include <hip/hip_fp16.h>

#define N_NODES 50000
#define NROW    50176                    // padded rows per graph (multiple of 1024)
#define N_EDGES 800000
#define BATCH   4
#define DIM     64
#define NEG_SLOPE 0.2f
#define K_CHUNK 16
#define CHUNK_E (N_EDGES / K_CHUNK)      // 50000 exactly
#define NTOT2   (BATCH * NROW)           // 200704 = 196*1024 exactly
#define SCAN_BLOCKS (NTOT2 / 1024)       // 196
#define HALF_ROWS 25088                  // NROW/2
#define HALF_WORDS 12544                 // HALF_ROWS/2 packed u16 words

// ---------------------------------------------------------------------------
// Index dtype detector (int64 vs int32): if int64 little-endian with values
// < 2^31, every odd 32-bit word is 0. flag=1 for int64, 0 for int32.
// ---------------------------------------------------------------------------
__global__ void detect_idx_kernel(const unsigned* __restrict__ ei, int* flag) {
    __shared__ int any;
    if (threadIdx.x == 0) any = 0;
    __syncthreads();
    unsigned v = ei[threadIdx.x * 2 + 1];
    if (v != 0) atomicOr(&any, 1);
    __syncthreads();
    if (threadIdx.x == 0) *flag = (any ? 0 : 1);
}

__device__ __forceinline__ int load_idx(const void* p, long long i, int is64) {
    if (is64) return (int)(((const long long*)p)[i]);
    return ((const int*)p)[i];
}

// ---------------------------------------------------------------------------
// Histogram stage 1: private LDS histogram per (graph, chunk, row-half).
// u16 counters packed in u32. Coalesced dump, no global atomics.
// ---------------------------------------------------------------------------
__global__ __launch_bounds__(256)
void hist_partial_kernel(const void* __restrict__ ei, const int* __restrict__ flag,
                         unsigned* __restrict__ P32) {
    __shared__ unsigned lds[HALF_WORDS];          // 50 KB
    int t = threadIdx.x;
    int b = blockIdx.x >> 5;
    int k = (blockIdx.x >> 1) & (K_CHUNK - 1);
    int h = blockIdx.x & 1;
    for (int i = t; i < HALF_WORDS; i += 256) lds[i] = 0;
    __syncthreads();
    const int is64 = *flag;
    const int rowLo = h * HALF_ROWS;
    const long long base = (long long)b * 2LL * N_EDGES + (long long)k * CHUNK_E;
    for (int i = t; i < CHUNK_E; i += 256) {
        int row = load_idx(ei, base + i, is64);
        unsigned r = (unsigned)(row - rowLo);
        if (r < HALF_ROWS)
            atomicAdd(&lds[r >> 1], 1u << ((r & 1) * 16));
    }
    __syncthreads();
    unsigned* dst = P32 + (long long)(b * K_CHUNK + k) * (NROW / 2) + h * HALF_WORDS;
    for (int i = t; i < HALF_WORDS; i += 256) dst[i] = lds[i];
}

// ---------------------------------------------------------------------------
// Stage 2: per (b,row): deg = sum_k counts; convert P16 in place to the
// EXCLUSIVE prefix over chunks (u16) -> deterministic placement bases.
// ---------------------------------------------------------------------------
__global__ __launch_bounds__(256)
void merge_prefix_kernel(unsigned short* __restrict__ P16, int* __restrict__ deg4) {
    int gid = blockIdx.x * 256 + threadIdx.x;
    if (gid >= NTOT2) return;
    int b = gid / NROW;
    int row = gid - b * NROW;
    unsigned short* p = P16 + (long long)(b * K_CHUNK) * NROW + row;
    int run = 0;
#pragma unroll
    for (int k = 0; k < K_CHUNK; ++k) {
        int c = p[(long long)k * NROW];
        p[(long long)k * NROW] = (unsigned short)run;
        run += c;
    }
    deg4[gid] = run;
}

// ---------------------------------------------------------------------------
// Hierarchical exclusive scan over deg4[NTOT2] -> rowptr4.
// ---------------------------------------------------------------------------
__global__ __launch_bounds__(256)
void scan_partial_kernel(const int* __restrict__ deg, int* __restrict__ bsum) {
    __shared__ int sdata[256];
    int t = threadIdx.x;
    int base = blockIdx.x * 1024;
    int s = 0;
#pragma unroll
    for (int i = 0; i < 4; ++i) s += deg[base + i * 256 + t];
    sdata[t] = s;
    __syncthreads();
    for (int off = 128; off > 0; off >>= 1) {
        if (t < off) sdata[t] += sdata[t + off];
        __syncthreads();
    }
    if (t == 0) bsum[blockIdx.x] = sdata[0];
}

__global__ __launch_bounds__(256)
void scan_bsum_kernel(int* __restrict__ bsum, int* __restrict__ rowptr) {
    __shared__ int sdata[256];
    int t = threadIdx.x;
    int v = (t < SCAN_BLOCKS) ? bsum[t] : 0;
    sdata[t] = v;
    __syncthreads();
    for (int off = 1; off < 256; off <<= 1) {
        int x = (t >= off) ? sdata[t - off] : 0;
        __syncthreads();
        sdata[t] += x;
        __syncthreads();
    }
    if (t < SCAN_BLOCKS) bsum[t] = sdata[t] - v;
    if (t == 255) rowptr[NTOT2] = sdata[255];
}

__global__ __launch_bounds__(256)
void scan_apply_kernel(const int* __restrict__ deg, const int* __restrict__ bsum,
                       int* __restrict__ rowptr) {
    __shared__ int sdata[256];
    int t = threadIdx.x;
    int base = blockIdx.x * 1024 + t * 4;
    int4 q = *(const int4*)(deg + base);          // NTOT2 exact multiple of 1024
    int s = q.x + q.y + q.z + q.w;
    sdata[t] = s;
    __syncthreads();
    for (int off = 1; off < 256; off <<= 1) {
        int x = (t >= off) ? sdata[t - off] : 0;
        __syncthreads();
        sdata[t] += x;
        __syncthreads();
    }
    int run = bsum[blockIdx.x] + sdata[t] - s;
    rowptr[base + 0] = run; run += q.x;
    rowptr[base + 1] = run; run += q.y;
    rowptr[base + 2] = run; run += q.z;
    rowptr[base + 3] = run;
}

// ---------------------------------------------------------------------------
// Deterministic placement: NO global atomics. Block = (b, k-chunk, row-half).
// LDS u16 cursors (packed u32) start at P16 prefix; pos = rowptr[row] + my16.
// ---------------------------------------------------------------------------
__global__ __launch_bounds__(512)
void placement_kernel(const void* __restrict__ ei, const float* __restrict__ ew,
                      const int* __restrict__ flag,
                      const unsigned short* __restrict__ P16,
                      const int* __restrict__ rowptr4,
                      int2* __restrict__ colw, int bStart, int sub) {
    __shared__ unsigned lds[HALF_WORDS];          // 50 KB packed u16 cursors
    const int is64 = *flag;
    int b = bStart + (blockIdx.x >> 5);
    int k = (blockIdx.x >> 1) & (K_CHUNK - 1);
    int h = blockIdx.x & 1;
    const int rowLo = h * HALF_ROWS;
    const unsigned* psrc =
        (const unsigned*)(P16 + (long long)(b * K_CHUNK + k) * NROW + rowLo);
    for (int i = threadIdx.x; i < HALF_WORDS; i += 512) lds[i] = psrc[i];
    __syncthreads();
    const long long ebase = (long long)b * 2LL * N_EDGES + (long long)k * CHUNK_E;
    const float* ewb = ew + (long long)b * N_EDGES + (long long)k * CHUNK_E;
    const int* rp = rowptr4 + b * NROW;
    for (int i = threadIdx.x; i < CHUNK_E; i += 512) {
        int row = load_idx(ei, ebase + i, is64);
        unsigned r = (unsigned)(row - rowLo);
        if (r < HALF_ROWS) {
            int col = load_idx(ei, ebase + N_EDGES + i, is64);
            float w = ewb[i];
            unsigned old = atomicAdd(&lds[r >> 1], 1u << ((r & 1) * 16));
            int my = (int)((old >> ((r & 1) * 16)) & 0xffffu);
            int pos = rp[row] + my - sub;
            colw[pos] = make_int2(col, __float_as_int(w));
        }
    }
}

// ---------------------------------------------------------------------------
// S = act(X) @ W  -> fp16 output. W in LDS; thread = (row, col-quad).
// ---------------------------------------------------------------------------
template <bool LEAKY>
__global__ __launch_bounds__(256)
void gemm_kernel(const float* __restrict__ X, const float* __restrict__ W,
                 __half* __restrict__ S) {
    __shared__ float Wl[64 * 64];
    int t = threadIdx.x;
    for (int i = t; i < 64 * 64; i += 256) Wl[i] = W[i];
    __syncthreads();

    int dq = t & 15;
    int rl = t >> 4;
    int rowBase = blockIdx.x * 64;
    for (int r = rl; r < 64; r += 16) {
        int row = rowBase + r;
        if (row >= N_NODES) break;
        const float* xr = X + (long long)row * DIM;
        float4 acc = {0.f, 0.f, 0.f, 0.f};
#pragma unroll
        for (int k = 0; k < 64; k += 4) {
            float4 xv = *(const float4*)(xr + k);
            if (LEAKY) {
                xv.x = xv.x > 0.f ? xv.x : NEG_SLOPE * xv.x;
                xv.y = xv.y > 0.f ? xv.y : NEG_SLOPE * xv.y;
                xv.z = xv.z > 0.f ? xv.z : NEG_SLOPE * xv.z;
                xv.w = xv.w > 0.f ? xv.w : NEG_SLOPE * xv.w;
            }
#pragma unroll
            for (int kk = 0; kk < 4; ++kk) {
                float xs = kk == 0 ? xv.x : kk == 1 ? xv.y : kk == 2 ? xv.z : xv.w;
                float4 wv = *(const float4*)(&Wl[(k + kk) * 64 + dq * 4]);
                acc.x += xs * wv.x;
                acc.y += xs * wv.y;
                acc.z += xs * wv.z;
                acc.w += xs * wv.w;
            }
        }
        __half2* o = (__half2*)(S + (long long)row * DIM + dq * 4);
        o[0] = __floats2half2_rn(acc.x, acc.y);
        o[1] = __floats2half2_rn(acc.z, acc.w);
    }
}

// ---------------------------------------------------------------------------
// Pull aggregation (fp16 src, f32 accum): wave per node, lane = feature.
// ---------------------------------------------------------------------------
__global__ __launch_bounds__(256)
void aggregate_kernel(const int* __restrict__ rowptr4, const int2* __restrict__ colw,
                      const __half* __restrict__ src, const float* __restrict__ bias,
                      float* __restrict__ dstBase, int bStart, int colwLocal) {
    const int BLKS = NROW / 4;                     // 12544
    int bi = blockIdx.x / BLKS;
    int node = (blockIdx.x % BLKS) * 4 + (threadIdx.x >> 6);
    int lane = threadIdx.x & 63;
    int b = bStart + bi;
    if (node >= N_NODES) return;
    const int* rp = rowptr4 + b * NROW;
    int sub = colwLocal ? b * N_EDGES : 0;
    int s = rp[node] - sub;
    int e = rp[node + 1] - sub;
    float acc = bias[lane];
    int k = s;
    for (; k + 8 <= e; k += 8) {
        int2 c[8];
        float v[8];
#pragma unroll
        for (int j = 0; j < 8; ++j) c[j] = colw[k + j];
#pragma unroll
        for (int j = 0; j < 8; ++j) v[j] = __half2float(src[(long long)c[j].x * DIM + lane]);
#pragma unroll
        for (int j = 0; j < 8; ++j) acc += __int_as_float(c[j].y) * v[j];
    }
    for (; k < e; ++k) {
        int2 c = colw[k];
        acc += __int_as_float(c.y) * __half2float(src[(long long)c.x * DIM + lane]);
    }
    dstBase[(long long)b * N_NODES * DIM + (long long)node * DIM + lane] = acc;
}

extern "C" void kernel_launch(void* const* d_in, const int* in_sizes, int n_in,
                              void* d_out, int out_size, void* d_ws, size_t ws_size,
                              hipStream_t stream) {
    const float* bx = (const float*)d_in[0];
    const void*  ei = d_in[1];
    const float* ew = (const float*)d_in[2];
    const float* W0 = (const float*)d_in[3];
    const float* b0 = (const float*)d_in[4];
    const float* W1 = (const float*)d_in[5];
    const float* b1 = (const float*)d_in[6];
    float* out = (float*)d_out;

    // ---- workspace layout (big path = 40.03 MB; R5 proved >= 40.8 MB) ----
    char* ws = (char*)d_ws;
    int*      flag     = (int*)ws;                       // [0,256)
    int*      bsum     = (int*)(ws + 256);               // [256,1280)
    int*      deg4     = (int*)(ws + 1280);              // [1280,804096)
    int*      rowptr4  = (int*)(ws + 804096);            // [804096,1607168)
    unsigned* P32      = (unsigned*)(ws + 1607168);      // [1607168,8029696) 6.42MB
    unsigned short* P16 = (unsigned short*)P32;
    __half*   support0 = (__half*)(ws + 8029696);        // 6.4 MB
    int2*     colw     = (int2*)(ws + 14429696);         // big: 25.6 MB
    const size_t NEED_BIG = 14429696ull + (size_t)BATCH * N_EDGES * 8ull; // 40.03MB
    const bool big = ws_size >= NEED_BIG;
    // support1: big path aliases P16 (dead after placement); small path sits
    // after the per-graph colw (total 27.2 MB).
    __half* support1 = big ? (__half*)P32
                           : (__half*)(ws + 14429696 + (size_t)N_EDGES * 8);
    const long long ND = (long long)N_NODES * DIM;

    detect_idx_kernel<<<1, 64, 0, stream>>>((const unsigned*)ei, flag);

    // ---- batched atomic-free CSR skeleton ----
    hist_partial_kernel<<<BATCH * K_CHUNK * 2, 256, 0, stream>>>(ei, flag, P32);
    merge_prefix_kernel<<<(NTOT2 + 255) / 256, 256, 0, stream>>>(P16, deg4);
    scan_partial_kernel<<<SCAN_BLOCKS, 256, 0, stream>>>(deg4, bsum);
    scan_bsum_kernel<<<1, 256, 0, stream>>>(bsum, rowptr4);
    scan_apply_kernel<<<SCAN_BLOCKS, 256, 0, stream>>>(deg4, bsum, rowptr4);

    // ---- layer-1 support (graph-independent, fp16) ----
    gemm_kernel<false><<<(N_NODES + 63) / 64, 256, 0, stream>>>(bx, W0, support0);

    const int AGG_BLKS = NROW / 4;                 // 12544 per graph

    if (big) {
        placement_kernel<<<BATCH * K_CHUNK * 2, 512, 0, stream>>>(
            ei, ew, flag, P16, rowptr4, colw, 0, 0);
        aggregate_kernel<<<BATCH * AGG_BLKS, 256, 0, stream>>>(
            rowptr4, colw, support0, b0, out, 0, 0);
        for (int b = 0; b < BATCH; ++b) {
            gemm_kernel<true><<<(N_NODES + 63) / 64, 256, 0, stream>>>(
                out + (long long)b * ND, W1, support1);   // P16 dead: placement done
            aggregate_kernel<<<AGG_BLKS, 256, 0, stream>>>(
                rowptr4, colw, support1, b1, out, b, 0);
        }
    } else {
        for (int b = 0; b < BATCH; ++b) {
            placement_kernel<<<K_CHUNK * 2, 512, 0, stream>>>(
                ei, ew, flag, P16, rowptr4, colw, b, b * N_EDGES);
            aggregate_kernel<<<AGG_BLKS, 256, 0, stream>>>(
                rowptr4, colw, support0, b0, out, b, 1);
            gemm_kernel<true><<<(N_NODES + 63) / 64, 256, 0, stream>>>(
                out + (long long)b * ND, W1, support1);
            aggregate_kernel<<<AGG_BLKS, 256, 0, stream>>>(
                rowptr4, colw, support1, b1, out, b, 1);
        }
    }
}

// Round 7
// 530.853 us; speedup vs baseline: 2.3759x; 1.0011x over previous
//
#include <hip/hip_runtime.h>
#include <hip/hip_fp16.h>

#define N_NODES 50000
#define NROW    50176                    // padded rows per graph (multiple of 1024)
#define N_EDGES 800000
#define BATCH   4
#define DIM     64
#define NEG_SLOPE 0.2f
#define K_CHUNK 16
#define CHUNK_E (N_EDGES / K_CHUNK)      // 50000 exactly
#define NTOT2   (BATCH * NROW)           // 200704 = 196*1024 exactly
#define SCAN_BLOCKS (NTOT2 / 1024)       // 196
#define HALF_ROWS 25088                  // NROW/2
#define HALF_WORDS 12544                 // HALF_ROWS/2 packed u16 words

// ---------------------------------------------------------------------------
// Index dtype detector (int64 vs int32): if int64 little-endian with values
// < 2^31, every odd 32-bit word is 0. flag=1 for int64, 0 for int32.
// ---------------------------------------------------------------------------
__global__ void detect_idx_kernel(const unsigned* __restrict__ ei, int* flag) {
    __shared__ int any;
    if (threadIdx.x == 0) any = 0;
    __syncthreads();
    unsigned v = ei[threadIdx.x * 2 + 1];
    if (v != 0) atomicOr(&any, 1);
    __syncthreads();
    if (threadIdx.x == 0) *flag = (any ? 0 : 1);
}

__device__ __forceinline__ int load_idx(const void* p, long long i, int is64) {
    if (is64) return (int)(((const long long*)p)[i]);
    return ((const int*)p)[i];
}

// ---------------------------------------------------------------------------
// Histogram stage 1: private LDS histogram per (graph, chunk, row-half).
// u16 counters packed in u32. Coalesced dump, no global atomics.
// ---------------------------------------------------------------------------
__global__ __launch_bounds__(256)
void hist_partial_kernel(const void* __restrict__ ei, const int* __restrict__ flag,
                         unsigned* __restrict__ P32) {
    __shared__ unsigned lds[HALF_WORDS];          // 50 KB
    int t = threadIdx.x;
    int b = blockIdx.x >> 5;
    int k = (blockIdx.x >> 1) & (K_CHUNK - 1);
    int h = blockIdx.x & 1;
    for (int i = t; i < HALF_WORDS; i += 256) lds[i] = 0;
    __syncthreads();
    const int is64 = *flag;
    const int rowLo = h * HALF_ROWS;
    const long long base = (long long)b * 2LL * N_EDGES + (long long)k * CHUNK_E;
    for (int i = t; i < CHUNK_E; i += 256) {
        int row = load_idx(ei, base + i, is64);
        unsigned r = (unsigned)(row - rowLo);
        if (r < HALF_ROWS)
            atomicAdd(&lds[r >> 1], 1u << ((r & 1) * 16));
    }
    __syncthreads();
    unsigned* dst = P32 + (long long)(b * K_CHUNK + k) * (NROW / 2) + h * HALF_WORDS;
    for (int i = t; i < HALF_WORDS; i += 256) dst[i] = lds[i];
}

// ---------------------------------------------------------------------------
// Stage 2: per (b,row): deg = sum_k counts; convert P16 in place to the
// EXCLUSIVE prefix over chunks (u16) -> deterministic placement bases.
// ---------------------------------------------------------------------------
__global__ __launch_bounds__(256)
void merge_prefix_kernel(unsigned short* __restrict__ P16, int* __restrict__ deg4) {
    int gid = blockIdx.x * 256 + threadIdx.x;
    if (gid >= NTOT2) return;
    int b = gid / NROW;
    int row = gid - b * NROW;
    unsigned short* p = P16 + (long long)(b * K_CHUNK) * NROW + row;
    int run = 0;
#pragma unroll
    for (int k = 0; k < K_CHUNK; ++k) {
        int c = p[(long long)k * NROW];
        p[(long long)k * NROW] = (unsigned short)run;
        run += c;
    }
    deg4[gid] = run;
}

// ---------------------------------------------------------------------------
// Hierarchical exclusive scan over deg4[NTOT2] -> rowptr4.
// ---------------------------------------------------------------------------
__global__ __launch_bounds__(256)
void scan_partial_kernel(const int* __restrict__ deg, int* __restrict__ bsum) {
    __shared__ int sdata[256];
    int t = threadIdx.x;
    int base = blockIdx.x * 1024;
    int s = 0;
#pragma unroll
    for (int i = 0; i < 4; ++i) s += deg[base + i * 256 + t];
    sdata[t] = s;
    __syncthreads();
    for (int off = 128; off > 0; off >>= 1) {
        if (t < off) sdata[t] += sdata[t + off];
        __syncthreads();
    }
    if (t == 0) bsum[blockIdx.x] = sdata[0];
}

__global__ __launch_bounds__(256)
void scan_bsum_kernel(int* __restrict__ bsum, int* __restrict__ rowptr) {
    __shared__ int sdata[256];
    int t = threadIdx.x;
    int v = (t < SCAN_BLOCKS) ? bsum[t] : 0;
    sdata[t] = v;
    __syncthreads();
    for (int off = 1; off < 256; off <<= 1) {
        int x = (t >= off) ? sdata[t - off] : 0;
        __syncthreads();
        sdata[t] += x;
        __syncthreads();
    }
    if (t < SCAN_BLOCKS) bsum[t] = sdata[t] - v;
    if (t == 255) rowptr[NTOT2] = sdata[255];
}

__global__ __launch_bounds__(256)
void scan_apply_kernel(const int* __restrict__ deg, const int* __restrict__ bsum,
                       int* __restrict__ rowptr) {
    __shared__ int sdata[256];
    int t = threadIdx.x;
    int base = blockIdx.x * 1024 + t * 4;
    int4 q = *(const int4*)(deg + base);          // NTOT2 exact multiple of 1024
    int s = q.x + q.y + q.z + q.w;
    sdata[t] = s;
    __syncthreads();
    for (int off = 1; off < 256; off <<= 1) {
        int x = (t >= off) ? sdata[t - off] : 0;
        __syncthreads();
        sdata[t] += x;
        __syncthreads();
    }
    int run = bsum[blockIdx.x] + sdata[t] - s;
    rowptr[base + 0] = run; run += q.x;
    rowptr[base + 1] = run; run += q.y;
    rowptr[base + 2] = run; run += q.z;
    rowptr[base + 3] = run;
}

// ---------------------------------------------------------------------------
// Deterministic placement: NO global atomics. Block = (b, k-chunk, row-half).
// LDS u16 cursors (packed u32) start at P16 prefix; pos = rowptr[row] + my16.
// ---------------------------------------------------------------------------
__global__ __launch_bounds__(512)
void placement_kernel(const void* __restrict__ ei, const float* __restrict__ ew,
                      const int* __restrict__ flag,
                      const unsigned short* __restrict__ P16,
                      const int* __restrict__ rowptr4,
                      int2* __restrict__ colw, int bStart, int sub) {
    __shared__ unsigned lds[HALF_WORDS];          // 50 KB packed u16 cursors
    const int is64 = *flag;
    int b = bStart + (blockIdx.x >> 5);
    int k = (blockIdx.x >> 1) & (K_CHUNK - 1);
    int h = blockIdx.x & 1;
    const int rowLo = h * HALF_ROWS;
    const unsigned* psrc =
        (const unsigned*)(P16 + (long long)(b * K_CHUNK + k) * NROW + rowLo);
    for (int i = threadIdx.x; i < HALF_WORDS; i += 512) lds[i] = psrc[i];
    __syncthreads();
    const long long ebase = (long long)b * 2LL * N_EDGES + (long long)k * CHUNK_E;
    const float* ewb = ew + (long long)b * N_EDGES + (long long)k * CHUNK_E;
    const int* rp = rowptr4 + b * NROW;
    for (int i = threadIdx.x; i < CHUNK_E; i += 512) {
        int row = load_idx(ei, ebase + i, is64);
        unsigned r = (unsigned)(row - rowLo);
        if (r < HALF_ROWS) {
            int col = load_idx(ei, ebase + N_EDGES + i, is64);
            float w = ewb[i];
            unsigned old = atomicAdd(&lds[r >> 1], 1u << ((r & 1) * 16));
            int my = (int)((old >> ((r & 1) * 16)) & 0xffffu);
            int pos = rp[row] + my - sub;
            colw[pos] = make_int2(col, __float_as_int(w));
        }
    }
}

// ---------------------------------------------------------------------------
// S = act(X) @ W  -> fp16 output. W in LDS; thread = (row, col-quad).
// ---------------------------------------------------------------------------
template <bool LEAKY>
__global__ __launch_bounds__(256)
void gemm_kernel(const float* __restrict__ X, const float* __restrict__ W,
                 __half* __restrict__ S) {
    __shared__ float Wl[64 * 64];
    int t = threadIdx.x;
    for (int i = t; i < 64 * 64; i += 256) Wl[i] = W[i];
    __syncthreads();

    int dq = t & 15;
    int rl = t >> 4;
    int rowBase = blockIdx.x * 64;
    for (int r = rl; r < 64; r += 16) {
        int row = rowBase + r;
        if (row >= N_NODES) break;
        const float* xr = X + (long long)row * DIM;
        float4 acc = {0.f, 0.f, 0.f, 0.f};
#pragma unroll
        for (int k = 0; k < 64; k += 4) {
            float4 xv = *(const float4*)(xr + k);
            if (LEAKY) {
                xv.x = xv.x > 0.f ? xv.x : NEG_SLOPE * xv.x;
                xv.y = xv.y > 0.f ? xv.y : NEG_SLOPE * xv.y;
                xv.z = xv.z > 0.f ? xv.z : NEG_SLOPE * xv.z;
                xv.w = xv.w > 0.f ? xv.w : NEG_SLOPE * xv.w;
            }
#pragma unroll
            for (int kk = 0; kk < 4; ++kk) {
                float xs = kk == 0 ? xv.x : kk == 1 ? xv.y : kk == 2 ? xv.z : xv.w;
                float4 wv = *(const float4*)(&Wl[(k + kk) * 64 + dq * 4]);
                acc.x += xs * wv.x;
                acc.y += xs * wv.y;
                acc.z += xs * wv.z;
                acc.w += xs * wv.w;
            }
        }
        __half2* o = (__half2*)(S + (long long)row * DIM + dq * 4);
        o[0] = __floats2half2_rn(acc.x, acc.y);
        o[1] = __floats2half2_rn(acc.z, acc.w);
    }
}

// ---------------------------------------------------------------------------
// Pull aggregation v2: wave per node, TWO edges in flight per wave.
// Lanes 0-31 process even edges, lanes 32-63 odd edges; each lane owns a
// dim-pair and gathers 4B __half2. One unrolled iter = 8 gathers = 16 edges.
// Combine slots via shfl_xor(32); lanes<32 do coalesced float2 store.
// ---------------------------------------------------------------------------
__global__ __launch_bounds__(256)
void aggregate_kernel(const int* __restrict__ rowptr4, const int2* __restrict__ colw,
                      const __half* __restrict__ src, const float* __restrict__ bias,
                      float* __restrict__ dstBase, int bStart, int colwLocal) {
    const int BLKS = NROW / 4;                     // 12544
    int bi = blockIdx.x / BLKS;
    int node = (blockIdx.x % BLKS) * 4 + (threadIdx.x >> 6);
    int tl = threadIdx.x & 63;
    int lane = tl & 31;                            // dim pair id (dims 2l, 2l+1)
    int slot = tl >> 5;                            // 0: even edges, 1: odd edges
    int b = bStart + bi;
    if (node >= N_NODES) return;
    const int* rp = rowptr4 + b * NROW;
    int sub = colwLocal ? b * N_EDGES : 0;
    int s = rp[node] - sub;
    int e = rp[node + 1] - sub;
    float2 acc = {0.f, 0.f};
    int k = s + slot;
    for (; k + 14 < e; k += 16) {                  // 8 pair-steps = 16 edges/wave
        int2 c[8];
        float2 v[8];
#pragma unroll
        for (int j = 0; j < 8; ++j) c[j] = colw[k + 2 * j];
#pragma unroll
        for (int j = 0; j < 8; ++j) {
            __half2 h = *(const __half2*)(src + (long long)c[j].x * DIM + 2 * lane);
            v[j] = __half22float2(h);
        }
#pragma unroll
        for (int j = 0; j < 8; ++j) {
            float w = __int_as_float(c[j].y);
            acc.x += w * v[j].x;
            acc.y += w * v[j].y;
        }
    }
    for (; k < e; k += 2) {
        int2 c = colw[k];
        __half2 h = *(const __half2*)(src + (long long)c.x * DIM + 2 * lane);
        float2 v = __half22float2(h);
        float w = __int_as_float(c.y);
        acc.x += w * v.x;
        acc.y += w * v.y;
    }
    acc.x += __shfl_xor(acc.x, 32, 64);
    acc.y += __shfl_xor(acc.y, 32, 64);
    if (slot == 0) {
        float2 bb = *(const float2*)(bias + 2 * lane);
        float2 o;
        o.x = acc.x + bb.x;
        o.y = acc.y + bb.y;
        *(float2*)(dstBase + (long long)b * N_NODES * DIM +
                   (long long)node * DIM + 2 * lane) = o;
    }
}

extern "C" void kernel_launch(void* const* d_in, const int* in_sizes, int n_in,
                              void* d_out, int out_size, void* d_ws, size_t ws_size,
                              hipStream_t stream) {
    const float* bx = (const float*)d_in[0];
    const void*  ei = d_in[1];
    const float* ew = (const float*)d_in[2];
    const float* W0 = (const float*)d_in[3];
    const float* b0 = (const float*)d_in[4];
    const float* W1 = (const float*)d_in[5];
    const float* b1 = (const float*)d_in[6];
    float* out = (float*)d_out;

    // ---- workspace layout (big path = 40.03 MB) ----
    char* ws = (char*)d_ws;
    int*      flag     = (int*)ws;                       // [0,256)
    int*      bsum     = (int*)(ws + 256);               // [256,1280)
    int*      deg4     = (int*)(ws + 1280);              // [1280,804096)
    int*      rowptr4  = (int*)(ws + 804096);            // [804096,1607168)
    unsigned* P32      = (unsigned*)(ws + 1607168);      // [1607168,8029696) 6.42MB
    unsigned short* P16 = (unsigned short*)P32;
    __half*   support0 = (__half*)(ws + 8029696);        // 6.4 MB
    int2*     colw     = (int2*)(ws + 14429696);         // big: 25.6 MB
    const size_t NEED_BIG = 14429696ull + (size_t)BATCH * N_EDGES * 8ull; // 40.03MB
    const bool big = ws_size >= NEED_BIG;
    __half* support1 = big ? (__half*)P32
                           : (__half*)(ws + 14429696 + (size_t)N_EDGES * 8);
    const long long ND = (long long)N_NODES * DIM;

    detect_idx_kernel<<<1, 64, 0, stream>>>((const unsigned*)ei, flag);

    // ---- batched atomic-free CSR skeleton ----
    hist_partial_kernel<<<BATCH * K_CHUNK * 2, 256, 0, stream>>>(ei, flag, P32);
    merge_prefix_kernel<<<(NTOT2 + 255) / 256, 256, 0, stream>>>(P16, deg4);
    scan_partial_kernel<<<SCAN_BLOCKS, 256, 0, stream>>>(deg4, bsum);
    scan_bsum_kernel<<<1, 256, 0, stream>>>(bsum, rowptr4);
    scan_apply_kernel<<<SCAN_BLOCKS, 256, 0, stream>>>(deg4, bsum, rowptr4);

    // ---- layer-1 support (graph-independent, fp16) ----
    gemm_kernel<false><<<(N_NODES + 63) / 64, 256, 0, stream>>>(bx, W0, support0);

    const int AGG_BLKS = NROW / 4;                 // 12544 per graph

    if (big) {
        placement_kernel<<<BATCH * K_CHUNK * 2, 512, 0, stream>>>(
            ei, ew, flag, P16, rowptr4, colw, 0, 0);
        aggregate_kernel<<<BATCH * AGG_BLKS, 256, 0, stream>>>(
            rowptr4, colw, support0, b0, out, 0, 0);
        for (int b = 0; b < BATCH; ++b) {
            gemm_kernel<true><<<(N_NODES + 63) / 64, 256, 0, stream>>>(
                out + (long long)b * ND, W1, support1);   // P16 dead: placement done
            aggregate_kernel<<<AGG_BLKS, 256, 0, stream>>>(
                rowptr4, colw, support1, b1, out, b, 0);
        }
    } else {
        for (int b = 0; b < BATCH; ++b) {
            placement_kernel<<<K_CHUNK * 2, 512, 0, stream>>>(
                ei, ew, flag, P16, rowptr4, colw, b, b * N_EDGES);
            aggregate_kernel<<<AGG_BLKS, 256, 0, stream>>>(
                rowptr4, colw, support0, b0, out, b, 1);
            gemm_kernel<true><<<(N_NODES + 63) / 64, 256, 0, stream>>>(
                out + (long long)b * ND, W1, support1);
            aggregate_kernel<<<AGG_BLKS, 256, 0, stream>>>(
                rowptr4, colw, support1, b1, out, b, 1);
        }
    }
}